// Round 3
// baseline (505.044 us; speedup 1.0000x reference)
//
#include <hip/hip_runtime.h>
#include <math.h>

// Problem constants
#define Bb   4
#define Ss   1024
#define Ee   1024
#define Nn   16
#define Hh   64
#define Ff   4096
#define Rr   2048
#define NHh  1024   // N*H
#define BSs  4096   // B*S
#define QKVLD 3072  // fused qkv row stride

typedef short v8s __attribute__((ext_vector_type(8)));
typedef float v4f __attribute__((ext_vector_type(4)));
typedef unsigned short v4us __attribute__((ext_vector_type(4)));
typedef unsigned int u32;
typedef unsigned short us;

static __device__ inline us f2bf(float f) {
    u32 u = __builtin_bit_cast(u32, f);
    u += 0x7fffu + ((u >> 16) & 1u);   // RNE
    return (us)(u >> 16);
}
static __device__ inline float bf2f(us h) {
    u32 u = ((u32)h) << 16;
    return __builtin_bit_cast(float, u);
}
static __device__ inline void g2lds16(const void* g, void* l) {
    __builtin_amdgcn_global_load_lds(
        (const __attribute__((address_space(1))) u32*)g,
        (__attribute__((address_space(3))) u32*)l, 16, 0, 0);
}

// ---------------------------------------------------------------------------
// Transpose + cvt core: in [K][N] fp32 -> out [N][K] bf16, 32x32 tile.
// ---------------------------------------------------------------------------
static __device__ __forceinline__ void tr_core(
    float (*t)[33],
    const float* __restrict__ in, us* __restrict__ out,
    int K, int N, int i0, int j0)
{
    const int r  = threadIdx.x >> 3;
    const int c4 = (threadIdx.x & 7) * 4;
    const float4 v = *reinterpret_cast<const float4*>(in + (size_t)(i0 + r) * N + j0 + c4);
    t[r][c4 + 0] = v.x; t[r][c4 + 1] = v.y; t[r][c4 + 2] = v.z; t[r][c4 + 3] = v.w;
    __syncthreads();
    ushort4 o;
    o.x = f2bf(t[c4 + 0][r]); o.y = f2bf(t[c4 + 1][r]);
    o.z = f2bf(t[c4 + 2][r]); o.w = f2bf(t[c4 + 3][r]);
    *reinterpret_cast<ushort4*>(out + (size_t)(j0 + r) * K + i0 + c4) = o;
}

// ---------------------------------------------------------------------------
// One merged prep kernel: x/rpe cvt (blocks [0,12288)), 5 square weight
// transposes ([12288,17408)), Wi/Wout transposes ([17408,25600)).
// ---------------------------------------------------------------------------
__global__ __launch_bounds__(256) void prep_all(
    const float* __restrict__ x, us* __restrict__ x16,
    const float* __restrict__ rpe, us* __restrict__ rpe16,
    const float* __restrict__ Wq, const float* __restrict__ Wk,
    const float* __restrict__ Wv, const float* __restrict__ Wr,
    const float* __restrict__ Wo,
    us* __restrict__ Wqkv_t, us* __restrict__ Wr_t, us* __restrict__ Wo_t,
    const float* __restrict__ Wi, us* __restrict__ Wi_t,
    const float* __restrict__ Wout, us* __restrict__ Wout_t)
{
    __shared__ float t[32][33];
    const int bid = blockIdx.x;
    if (bid < 12288) {
        const float* in; us* out; size_t base;
        if (bid < 4096) { in = x; out = x16; base = (size_t)bid; }
        else { in = rpe; out = rpe16; base = (size_t)(bid - 4096); }
        const size_t i = (base * 256 + threadIdx.x) * 4;
        const float4 v = *reinterpret_cast<const float4*>(in + i);
        ushort4 o;
        o.x = f2bf(v.x); o.y = f2bf(v.y); o.z = f2bf(v.z); o.w = f2bf(v.w);
        *reinterpret_cast<ushort4*>(out + i) = o;
    } else if (bid < 17408) {
        const int local = bid - 12288;
        const int z = local >> 10;
        const int rem = local & 1023;
        const int i0 = (rem >> 5) * 32;
        const int j0 = (rem & 31) * 32;
        const float* in; us* out;
        switch (z) {
            case 0: in = Wq; out = Wqkv_t; break;
            case 1: in = Wk; out = Wqkv_t + 1024 * 1024; break;
            case 2: in = Wv; out = Wqkv_t + 2048 * 1024; break;
            case 3: in = Wr; out = Wr_t; break;
            default: in = Wo; out = Wo_t; break;
        }
        tr_core(t, in, out, 1024, 1024, i0, j0);
    } else {
        const int local = bid - 17408;
        if (local < 4096) {
            const int xb = local & 127, yb = local >> 7;
            tr_core(t, Wi, Wi_t, 1024, 4096, yb * 32, xb * 32);
        } else {
            const int l2 = local - 4096;
            const int xb = l2 & 127, yb = l2 >> 7;
            tr_core(t, Wout, Wout_t, 4096, 1024, xb * 32, yb * 32);
        }
    }
}

// ---------------------------------------------------------------------------
// Per-(b,n) transpose of V: v16 (stride ld) [B,S,*] -> vT16 [B,N,H,S] bf16.
// ---------------------------------------------------------------------------
__global__ __launch_bounds__(256) void transpose_v(
    const us* __restrict__ v16, us* __restrict__ vT16, int ld)
{
    __shared__ us T[64][72];
    const int s0 = blockIdx.x * 64;
    const int bn = blockIdx.y;          // b*16 + n
    const int b  = bn >> 4, n = bn & 15;
    const int t  = threadIdx.x;
    {
        const int r = t >> 2, c = (t & 3) * 16;
        const uint4* src = (const uint4*)(v16 + (size_t)(b * Ss + s0 + r) * ld + n * 64 + c);
        *(uint4*)&T[r][c]     = src[0];
        *(uint4*)&T[r][c + 8] = src[1];
    }
    __syncthreads();
    {
        const int h = t >> 2, c2 = (t & 3) * 16;
        us tmp[16];
        #pragma unroll
        for (int u = 0; u < 16; ++u) tmp[u] = T[c2 + u][h];
        us* dst = vT16 + (size_t)(bn * 64 + h) * Ss + s0 + c2;
        *(uint4*)dst       = *(uint4*)tmp;
        *(uint4*)(dst + 8) = *(uint4*)(tmp + 8);
    }
}

// ---------------------------------------------------------------------------
// bf16 MFMA GEMM body: C = A[M,K] @ B^T (B as [N][K]).
// Tile: (MT*32) x 128, BK=64, 4 waves 2x2; XOR-swizzled LDS (see R6/R7).
// ---------------------------------------------------------------------------
template<int MT, int OUT_BF16, int BIAS, int RELU>
static __device__ __forceinline__ void gemm_body(
    us* __restrict__ Asm, us* __restrict__ Bsm,
    const us* __restrict__ A, const us* __restrict__ B,
    const float* __restrict__ bias, void* __restrict__ Cv,
    int K, int ldC, int row0, int col0)
{
    const int tid  = threadIdx.x;
    const int lane = tid & 63;
    const int wave = tid >> 6;
    const int wr   = wave >> 1, wc = wave & 1;
    const int lrow = lane & 15;
    const int lq   = lane >> 4;
    const int h3   = lrow & 7;

    v4f acc[MT][4];
    #pragma unroll
    for (int mt = 0; mt < MT; ++mt)
        #pragma unroll
        for (int nt = 0; nt < 4; ++nt)
            acc[mt][nt] = (v4f){0.f, 0.f, 0.f, 0.f};

    for (int k0 = 0; k0 < K; k0 += 64) {
        #pragma unroll
        for (int u = 0; u < MT; ++u) {
            const int slot = u * 256 + tid;
            const int sr = slot >> 3;
            const int sc = ((slot & 7) ^ (sr & 7)) * 8;
            g2lds16(A + (size_t)(row0 + sr) * K + k0 + sc, &Asm[slot * 8]);
        }
        #pragma unroll
        for (int u = 0; u < 4; ++u) {
            const int slot = u * 256 + tid;
            const int sr = slot >> 3;
            const int sc = ((slot & 7) ^ (sr & 7)) * 8;
            g2lds16(B + (size_t)(col0 + sr) * K + k0 + sc, &Bsm[slot * 8]);
        }
        __syncthreads();

        #pragma unroll
        for (int t = 0; t < 2; ++t) {
            const int cc = ((lq + 4 * t) ^ h3) * 8;
            v8s af[MT], bf[4];
            #pragma unroll
            for (int mt = 0; mt < MT; ++mt)
                af[mt] = *reinterpret_cast<const v8s*>(
                    &Asm[(wr * (MT * 16) + mt * 16 + lrow) * 64 + cc]);
            #pragma unroll
            for (int nt = 0; nt < 4; ++nt)
                bf[nt] = *reinterpret_cast<const v8s*>(
                    &Bsm[(wc * 64 + nt * 16 + lrow) * 64 + cc]);
            #pragma unroll
            for (int mt = 0; mt < MT; ++mt)
                #pragma unroll
                for (int nt = 0; nt < 4; ++nt)
                    acc[mt][nt] = __builtin_amdgcn_mfma_f32_16x16x32_bf16(
                        af[mt], bf[nt], acc[mt][nt], 0, 0, 0);
        }
        __syncthreads();
    }

    #pragma unroll
    for (int nt = 0; nt < 4; ++nt) {
        const int col = col0 + wc * 64 + nt * 16 + lrow;
        const float bv = BIAS ? bias[col] : 0.f;
        #pragma unroll
        for (int mt = 0; mt < MT; ++mt) {
            #pragma unroll
            for (int v = 0; v < 4; ++v) {
                const int row = row0 + wr * (MT * 16) + mt * 16 + lq * 4 + v;
                float val = acc[mt][nt][v] + bv;
                if (RELU) val = fmaxf(val, 0.f);
                if (OUT_BF16)
                    ((us*)Cv)[(size_t)row * ldC + col] = f2bf(val);
                else
                    ((float*)Cv)[(size_t)row * ldC + col] = val;
            }
        }
    }
}

template<int MT, int OUT_BF16, int BIAS, int RELU>
__global__ __launch_bounds__(256) void gemm_tile(
    const us* __restrict__ A, const us* __restrict__ B,
    const float* __restrict__ bias, void* __restrict__ Cv,
    int K, int ldC)
{
    __shared__ us Asm[MT * 32 * 64];
    __shared__ us Bsm[128 * 64];
    gemm_body<MT, OUT_BF16, BIAS, RELU>(Asm, Bsm, A, B, bias, Cv, K, ldC,
                                        blockIdx.y * (MT * 32), blockIdx.x * 128);
}

// Fused QKV (768 blocks) + R (512 blocks) projection in one 1280-block launch.
__global__ __launch_bounds__(256) void gemm_qkv_r(
    const us* __restrict__ x16, const us* __restrict__ Wqkv,
    us* __restrict__ qkv, const us* __restrict__ rpe16,
    const us* __restrict__ Wr, us* __restrict__ rout)
{
    __shared__ us Asm[128 * 64];
    __shared__ us Bsm[128 * 64];
    const int bid = blockIdx.x;
    if (bid < 768) {
        gemm_body<4,1,0,0>(Asm, Bsm, x16, Wqkv, nullptr, qkv, Ee, QKVLD,
                           (bid / 24) * 128, (bid % 24) * 128);
    } else {
        const int b2 = bid - 768;
        gemm_body<4,1,0,0>(Asm, Bsm, rpe16, Wr, nullptr, rout, Ee, NHh,
                           (b2 / 8) * 128, (b2 % 8) * 128);
    }
}

// ---------------------------------------------------------------------------
// MFMA flash attention with rel-shift ring buffer.
// R11: LDS 40960 -> 32768 B. Evidence (R8: 53760B -> occ 25.9% = 2.5-blk avg;
// R10: 40960B x4 = exact 163840 -> occ 32% = 2.5-blk avg) shows exact-fit
// allocation FAILS (reserved LDS), leaving 3 resident + 1-block tail. At
// 32 KB, 4 blocks fit with margin -> whole grid resident, no tail.
// The 8 KB shrink: drop the VtT stage; PV B-fragments are 16B-contiguous
// rows of vT16 in global, L2-hot (16 same-XCD blocks share each (b,n)
// panel), and consumed at iteration END -> per-lane direct loads issued at
// the loop TOP have the whole QK/pos/softmax phase (~1500 cy) to hide
// latency. (Unlike R9, where K was consumed right after its load.)
// Kept from R10: staged Kt/Rt with 16B-granule XOR swizzle, row-XOR ring,
// Pt overlay on Kt (B3 barrier), reg-built q-frags, exp2f, setprio on PV.
// ---------------------------------------------------------------------------
__global__ __launch_bounds__(256, 4) void attn_mfma(
    const us* __restrict__ qkv, const us* __restrict__ vT16,
    const us* __restrict__ r16,
    const float* __restrict__ cb, const float* __restrict__ pb,
    us* __restrict__ attn)
{
    __shared__ __align__(16) us smem[16384];    // 32768 B
    us* Kt   = smem;            // 64 x 64 swz (8192 B); overlaid by Pt
    us* Rt   = smem + 4096;     // 64 x 64 swz (8192 B)
    us* ring = smem + 8192;     // 128 cols x 64 rows, row-XOR swz (16384 B)
    us* Pt   = Kt;              // overlay

    const int bn = blockIdx.x;         // b*16 + n  (XCD = bn & 7)
    const int b  = bn >> 4;
    const int n  = bn & 15;
    const int i0 = blockIdx.y * 64;
    const int tid  = threadIdx.x;
    const int lane = tid & 63;
    const int w    = tid >> 6;
    const int quad = lane >> 4;
    const int l15  = lane & 15;
    const int l7   = l15 & 7;
    const int w16  = w * 16;

    const float SCALE = 0.125f * 1.44269504088896f;   // 1/sqrt(H) * log2(e)

    // ---- Prologue: A-fragments qc/qp built per-lane direct from global ----
    v8s aqc0, aqc1, aqp0, aqp1;
    {
        const us* qrow = qkv + (size_t)(b * Ss + i0 + w16 + l15) * QKVLD + n * 64;
        const v8s q0 = *(const v8s*)(qrow + quad * 8);
        const v8s q1 = *(const v8s*)(qrow + 32 + quad * 8);
        const float* cbp = cb + n * 64 + quad * 8;
        const float* pbp = pb + n * 64 + quad * 8;
        #pragma unroll
        for (int u = 0; u < 8; ++u) {
            const float f0 = bf2f((us)q0[u]);
            const float f1 = bf2f((us)q1[u]);
            aqc0[u] = (short)f2bf((f0 + cbp[u])      * SCALE);
            aqc1[u] = (short)f2bf((f1 + cbp[u + 32]) * SCALE);
            aqp0[u] = (short)f2bf((f0 + pbp[u])      * SCALE);
            aqp1[u] = (short)f2bf((f1 + pbp[u + 32]) * SCALE);
        }
    }

    const int c0 = Ss - i0;   // l at j-i diag base

    // Staging geometry (shared by bootstrap + main loop)
    const int sgr = tid >> 2;            // row 0..63
    const int scg = (tid & 3) * 2;       // first 16B granule (0,2,4,6)
    const int srx = sgr & 7;
    us* const kd0 = &Kt[sgr * 64 + ((scg ^ srx) << 3)];
    us* const kd1 = &Kt[sgr * 64 + (((scg + 1) ^ srx) << 3)];
    us* const rd0 = &Rt[sgr * 64 + ((scg ^ srx) << 3)];
    us* const rd1 = &Rt[sgr * 64 + (((scg + 1) ^ srx) << 3)];

    // ---- Bootstrap: pos chunk l in [c0-64, c0) -> ring cols j in [irow-i0-64, irow-i0) ----
    {
        const uint4* sr = (const uint4*)(r16 + (size_t)(b * Rr + (c0 - 64) + sgr) * NHh + n * 64 + scg * 8);
        uint4 r0v = sr[0], r1v = sr[1];
        *(uint4*)rd0 = r0v;
        *(uint4*)rd1 = r1v;
        __syncthreads();
        const v4f z = (v4f){0.f, 0.f, 0.f, 0.f};
        #pragma unroll
        for (int t = 0; t < 4; ++t) {
            const int row = t * 16 + l15;
            v8s br0 = *(const v8s*)&Rt[row * 64 + ((quad ^ l7) << 3)];
            v8s br1 = *(const v8s*)&Rt[row * 64 + (((quad + 4) ^ l7) << 3)];
            v4f pp = __builtin_amdgcn_mfma_f32_16x16x32_bf16(aqp0, br0, z, 0, 0, 0);
            pp = __builtin_amdgcn_mfma_f32_16x16x32_bf16(aqp1, br1, pp, 0, 0, 0);
            const int colbase = t * 16 + l15 - 64;   // j = colbase + irow
            #pragma unroll
            for (int v = 0; v < 4; ++v) {
                const int irow = w16 + quad * 4 + v;
                const int col = (colbase + irow) & 127;
                ring[col * 64 + (irow ^ ((col & 7) << 3))] = f2bf(pp[v]);
            }
        }
    }

    v4f Oa[4];
    #pragma unroll
    for (int t = 0; t < 4; ++t) Oa[t] = (v4f){0.f, 0.f, 0.f, 0.f};
    float la[4] = {0.f, 0.f, 0.f, 0.f};

    // Per-lane V base (direct global; row = bn*64 + h, col = j)
    const us* vbase = vT16 + (size_t)(bn * 64 + l15) * Ss + quad * 8;

    // ---- Main flash loop over key tiles ----
    for (int j0 = 0; j0 < Ss; j0 += 64) {
        // V direct loads issued FIRST -> latency hides under QK/pos/softmax
        v8s bv[4][2];
        #pragma unroll
        for (int ht = 0; ht < 4; ++ht) {
            const us* vt = vbase + (size_t)(ht * 16) * Ss + j0;
            bv[ht][0] = *(const v8s*)vt;
            bv[ht][1] = *(const v8s*)(vt + 32);
        }

        __syncthreads();   // B1: prev iter Pt reads + bootstrap Rt reads done
        {
            const uint4* sk = (const uint4*)(qkv + (size_t)(b * Ss + j0 + sgr) * QKVLD + NHh + n * 64 + scg * 8);
            const uint4* sr = (const uint4*)(r16 + (size_t)(b * Rr + (j0 + c0) + sgr) * NHh + n * 64 + scg * 8);
            uint4 k0v = sk[0], k1v = sk[1];
            uint4 r0v = sr[0], r1v = sr[1];
            *(uint4*)kd0 = k0v;  *(uint4*)kd1 = k1v;
            *(uint4*)rd0 = r0v;  *(uint4*)rd1 = r1v;
        }
        __syncthreads();   // B2: stage visible

        const v4f z = (v4f){0.f, 0.f, 0.f, 0.f};
        // Content scores
        v4f sc[4];
        #pragma unroll
        for (int t = 0; t < 4; ++t) {
            const int row = t * 16 + l15;
            v8s bk0 = *(const v8s*)&Kt[row * 64 + ((quad ^ l7) << 3)];
            v8s bk1 = *(const v8s*)&Kt[row * 64 + (((quad + 4) ^ l7) << 3)];
            sc[t] = __builtin_amdgcn_mfma_f32_16x16x32_bf16(aqc0, bk0, z, 0, 0, 0);
            sc[t] = __builtin_amdgcn_mfma_f32_16x16x32_bf16(aqc1, bk1, sc[t], 0, 0, 0);
        }
        // Pos chunk -> ring (skewed cm: col = j & 127, row-XOR swizzle)
        #pragma unroll
        for (int t = 0; t < 4; ++t) {
            const int row = t * 16 + l15;
            v8s br0 = *(const v8s*)&Rt[row * 64 + ((quad ^ l7) << 3)];
            v8s br1 = *(const v8s*)&Rt[row * 64 + (((quad + 4) ^ l7) << 3)];
            v4f pp = __builtin_amdgcn_mfma_f32_16x16x32_bf16(aqp0, br0, z, 0, 0, 0);
            pp = __builtin_amdgcn_mfma_f32_16x16x32_bf16(aqp1, br1, pp, 0, 0, 0);
            const int colbase = j0 + t * 16 + l15;
            #pragma unroll
            for (int v = 0; v < 4; ++v) {
                const int irow = w16 + quad * 4 + v;
                const int col = (colbase + irow) & 127;
                ring[col * 64 + (irow ^ ((col & 7) << 3))] = f2bf(pp[v]);
            }
        }

        __syncthreads();   // B3: all waves' Kt reads done -> Pt may overwrite

        // Scores -> exp2 -> Pt (=Kt); pos gathered via one b64 per t
        #pragma unroll
        for (int t = 0; t < 4; ++t) {
            const int col = (j0 + t * 16 + l15) & 127;
            const int rbase = (w16 + quad * 4) ^ ((col & 7) << 3);
            const v4us pr = *(const v4us*)&ring[col * 64 + rbase];
            const int j = t * 16 + l15;
            const int gsw = j >> 3;            // 2t + (l15>>3)
            #pragma unroll
            for (int v = 0; v < 4; ++v) {
                const int irow = w16 + quad * 4 + v;
                const float p = exp2f(sc[t][v] + bf2f(pr[v]));
                la[v] += p;
                Pt[irow * 64 + (((gsw ^ (irow & 7)) << 3) | (j & 7))] = f2bf(p);
            }
        }

        // PV (V from registers, loaded at loop top)
        v8s pa0 = *(v8s*)&Pt[(w16 + l15) * 64 + ((quad ^ l7) << 3)];
        v8s pa1 = *(v8s*)&Pt[(w16 + l15) * 64 + (((quad + 4) ^ l7) << 3)];
        __builtin_amdgcn_s_setprio(1);
        #pragma unroll
        for (int ht = 0; ht < 4; ++ht) {
            Oa[ht] = __builtin_amdgcn_mfma_f32_16x16x32_bf16(pa0, bv[ht][0], Oa[ht], 0, 0, 0);
            Oa[ht] = __builtin_amdgcn_mfma_f32_16x16x32_bf16(pa1, bv[ht][1], Oa[ht], 0, 0, 0);
        }
        __builtin_amdgcn_s_setprio(0);
    }

    // ---- Epilogue: reduce row sums across quad, normalize, store ----
    #pragma unroll
    for (int v = 0; v < 4; ++v) {
        la[v] += __shfl_xor(la[v], 1);
        la[v] += __shfl_xor(la[v], 2);
        la[v] += __shfl_xor(la[v], 4);
        la[v] += __shfl_xor(la[v], 8);
        la[v] = 1.f / la[v];
    }
    #pragma unroll
    for (int ht = 0; ht < 4; ++ht) {
        #pragma unroll
        for (int v = 0; v < 4; ++v) {
            const int irow = w16 + quad * 4 + v;
            attn[(size_t)(b * Ss + i0 + irow) * NHh + n * 64 + ht * 16 + l15] =
                f2bf(Oa[ht][v] * la[v]);
        }
    }
}

// ---------------------------------------------------------------------------
// Fused residual-add + LayerNorm over E=1024; optional bf16 copy of output.
// ---------------------------------------------------------------------------
template<int W16>
__global__ __launch_bounds__(256) void add_ln_kernel(
    const float* __restrict__ a, const float* __restrict__ res,
    const float* __restrict__ g, const float* __restrict__ bet,
    float* __restrict__ out, us* __restrict__ out16)
{
    const int row = blockIdx.x;
    const int tid = threadIdx.x;
    const float* ar = a   + (size_t)row * Ee;
    const float* rr = res + (size_t)row * Ee;

    float vals[4];
    float lsum = 0.f, lsq = 0.f;
    #pragma unroll
    for (int it = 0; it < 4; ++it) {
        const int idx = tid + it * 256;
        const float vv = ar[idx] + rr[idx];
        vals[it] = vv;
        lsum += vv;
        lsq  = fmaf(vv, vv, lsq);
    }
    #pragma unroll
    for (int off = 32; off > 0; off >>= 1) {
        lsum += __shfl_down(lsum, off);
        lsq  += __shfl_down(lsq,  off);
    }
    __shared__ float w1[4], w2[4];
    if ((tid & 63) == 0) { w1[tid >> 6] = lsum; w2[tid >> 6] = lsq; }
    __syncthreads();
    const float sum  = w1[0] + w1[1] + w1[2] + w1[3];
    const float sq   = w2[0] + w2[1] + w2[2] + w2[3];
    const float mean = sum * (1.f / 1024.f);
    const float var  = sq * (1.f / 1024.f) - mean * mean;
    const float rstd = rsqrtf(var + 1e-12f);
    #pragma unroll
    for (int it = 0; it < 4; ++it) {
        const int idx = tid + it * 256;
        const float o = (vals[it] - mean) * rstd * g[idx] + bet[idx];
        out[(size_t)row * Ee + idx] = o;
        if (W16) out16[(size_t)row * Ee + idx] = f2bf(o);
    }
}

// ---------------------------------------------------------------------------
// Orchestration. Workspace layout (1 MB units), 90 MB total:
//   [ 0, 8)  x16      -> attn16 (ph3)  -> inner16 head (ph6)
//   [ 8,24)  rpe16    -> vT16 [8,16) (ph2.5), ao fp32 [16,24) (ph4)
//   [24,30)  Wqkv_t   [30,32) Wr_t   [32,34) Wo_t      (inner16 covers 0..32)
//   [34,42)  Wi_t     [42,50) Wout_t
//   [50,74)  qkv16    -> h16 [50,58) + hb fp32 [58,74) (ph5)
//   [74,90)  r16      -> out2 fp32 (ph7)
// ---------------------------------------------------------------------------
#define MB (1u << 20)

extern "C" void kernel_launch(void* const* d_in, const int* in_sizes, int n_in,
                              void* d_out, int out_size, void* d_ws, size_t ws_size,
                              hipStream_t stream)
{
    (void)in_sizes; (void)n_in; (void)out_size; (void)ws_size;

    const float* x    = (const float*)d_in[0];
    const float* cbf  = (const float*)d_in[1];
    const float* pbf  = (const float*)d_in[2];
    const float* rpe  = (const float*)d_in[3];
    const float* Wq   = (const float*)d_in[4];
    const float* Wk   = (const float*)d_in[5];
    const float* Wv   = (const float*)d_in[6];
    const float* Wr   = (const float*)d_in[7];
    const float* Wo   = (const float*)d_in[8];
    const float* ln1g = (const float*)d_in[9];
    const float* ln1b = (const float*)d_in[10];
    const float* Wi   = (const float*)d_in[11];
    const float* bi   = (const float*)d_in[12];
    const float* Wout = (const float*)d_in[13];
    const float* bout = (const float*)d_in[14];
    const float* ln2g = (const float*)d_in[15];
    const float* ln2b = (const float*)d_in[16];

    float* out = (float*)d_out;
    char*  ws  = (char*)d_ws;

    us* x16    = (us*)(ws + 0 * MB);
    us* rpe16  = (us*)(ws + 8 * MB);
    us* Wqkv_t = (us*)(ws + 24 * MB);           // [3072][1024]
    us* Wr_t   = (us*)(ws + 30 * MB);
    us* Wo_t   = (us*)(ws + 32 * MB);
    us* Wi_t   = (us*)(ws + 34 * MB);
    us* Wout_t = (us*)(ws + 42 * MB);
    us* qkv16  = (us*)(ws + 50 * MB);           // [BS][3072]
    us* r16    = (us*)(ws + 74 * MB);
    us* vT16   = (us*)(ws + 8 * MB);            // reuse rpe16 (after qkv_r gemm)
    us* attn16 = (us*)(ws + 0 * MB);            // reuse x16
    float* ao  = (float*)(ws + 16 * MB);        // [16,24)
    us* h16    = (us*)(ws + 50 * MB);           // reuse qkv16
    float* hb  = (float*)(ws + 58 * MB);        // reuse qkv16 tail
    us* inner16= (us*)(ws + 0 * MB);            // 0..32 MB
    float* out2= (float*)(ws + 74 * MB);        // reuse r16

    const dim3 blk(256);

    // Phase 1: all converts + transposes, one dispatch
    prep_all<<<dim3(25600), blk, 0, stream>>>(
        x, x16, rpe, rpe16, Wq, Wk, Wv, Wr, Wo,
        Wqkv_t, Wr_t, Wo_t, Wi, Wi_t, Wout, Wout_t);

    // Phase 2: fused QKV + R projection (one 1280-block dispatch)
    gemm_qkv_r<<<dim3(1280), blk, 0, stream>>>(x16, Wqkv_t, qkv16, rpe16, Wr_t, r16);

    // Phase 2.5: V transpose (v cols of qkv) -> [B,N,H,S]
    transpose_v<<<dim3(16, 64), blk, 0, stream>>>(qkv16 + 2048, vT16, QKVLD);

    // Phase 3: MFMA flash attention; grid (bn, i) for XCD-local K/R/V reuse
    attn_mfma<<<dim3(64, 16), blk, 0, stream>>>(qkv16, vT16, r16, cbf, pbf, attn16);

    // Phase 4: output projection (fp32 out), 64-row tiles -> 512 blocks (2/CU)
    gemm_tile<2,0,0,0><<<dim3(8, 64), blk, 0, stream>>>(attn16, Wo_t, nullptr, ao, NHh, Ee);

    // Phase 5: h = LN1(ao + x), fp32 + bf16
    add_ln_kernel<1><<<dim3(BSs), blk, 0, stream>>>(ao, x, ln1g, ln1b, hb, h16);

    // Phase 6: FFN1 (bias+relu, bf16 out), 128-row tiles, 1024 blocks
    gemm_tile<4,1,1,1><<<dim3(32, 32), blk, 0, stream>>>(h16, Wi_t, bi, inner16, Ee, Ff);

    // Phase 7: FFN2 (bias, fp32 out), 64-row tiles -> 512 blocks (2+/CU)
    gemm_tile<2,0,1,0><<<dim3(8, 64), blk, 0, stream>>>(inner16, Wout_t, bout, out2, Ff, Ee);

    // Phase 8: out = LN2(out2 + h)
    add_ln_kernel<0><<<dim3(BSs), blk, 0, stream>>>(out2, hb, ln2g, ln2b, out, nullptr);
}

// Round 4
// 432.433 us; speedup vs baseline: 1.1679x; 1.1679x over previous
//
#include <hip/hip_runtime.h>
#include <math.h>

// Problem constants
#define Bb   4
#define Ss   1024
#define Ee   1024
#define Nn   16
#define Hh   64
#define Ff   4096
#define Rr   2048
#define NHh  1024   // N*H
#define BSs  4096   // B*S
#define QKVLD 3072  // fused qkv row stride

typedef short v8s __attribute__((ext_vector_type(8)));
typedef float v4f __attribute__((ext_vector_type(4)));
typedef unsigned short v4us __attribute__((ext_vector_type(4)));
typedef unsigned int u32;
typedef unsigned short us;

static __device__ inline us f2bf(float f) {
    u32 u = __builtin_bit_cast(u32, f);
    u += 0x7fffu + ((u >> 16) & 1u);   // RNE
    return (us)(u >> 16);
}
static __device__ inline float bf2f(us h) {
    u32 u = ((u32)h) << 16;
    return __builtin_bit_cast(float, u);
}
static __device__ inline void g2lds16(const void* g, void* l) {
    __builtin_amdgcn_global_load_lds(
        (const __attribute__((address_space(1))) u32*)g,
        (__attribute__((address_space(3))) u32*)l, 16, 0, 0);
}

// ---------------------------------------------------------------------------
// Transpose + cvt core: in [K][N] fp32 -> out [N][K] bf16, 32x32 tile.
// ---------------------------------------------------------------------------
static __device__ __forceinline__ void tr_core(
    float (*t)[33],
    const float* __restrict__ in, us* __restrict__ out,
    int K, int N, int i0, int j0)
{
    const int r  = threadIdx.x >> 3;
    const int c4 = (threadIdx.x & 7) * 4;
    const float4 v = *reinterpret_cast<const float4*>(in + (size_t)(i0 + r) * N + j0 + c4);
    t[r][c4 + 0] = v.x; t[r][c4 + 1] = v.y; t[r][c4 + 2] = v.z; t[r][c4 + 3] = v.w;
    __syncthreads();
    ushort4 o;
    o.x = f2bf(t[c4 + 0][r]); o.y = f2bf(t[c4 + 1][r]);
    o.z = f2bf(t[c4 + 2][r]); o.w = f2bf(t[c4 + 3][r]);
    *reinterpret_cast<ushort4*>(out + (size_t)(j0 + r) * K + i0 + c4) = o;
}

// ---------------------------------------------------------------------------
// One merged prep kernel: x/rpe cvt (blocks [0,12288)), 5 square weight
// transposes ([12288,17408)), Wi/Wout transposes ([17408,25600)).
// ---------------------------------------------------------------------------
__global__ __launch_bounds__(256) void prep_all(
    const float* __restrict__ x, us* __restrict__ x16,
    const float* __restrict__ rpe, us* __restrict__ rpe16,
    const float* __restrict__ Wq, const float* __restrict__ Wk,
    const float* __restrict__ Wv, const float* __restrict__ Wr,
    const float* __restrict__ Wo,
    us* __restrict__ Wqkv_t, us* __restrict__ Wr_t, us* __restrict__ Wo_t,
    const float* __restrict__ Wi, us* __restrict__ Wi_t,
    const float* __restrict__ Wout, us* __restrict__ Wout_t)
{
    __shared__ float t[32][33];
    const int bid = blockIdx.x;
    if (bid < 12288) {
        const float* in; us* out; size_t base;
        if (bid < 4096) { in = x; out = x16; base = (size_t)bid; }
        else { in = rpe; out = rpe16; base = (size_t)(bid - 4096); }
        const size_t i = (base * 256 + threadIdx.x) * 4;
        const float4 v = *reinterpret_cast<const float4*>(in + i);
        ushort4 o;
        o.x = f2bf(v.x); o.y = f2bf(v.y); o.z = f2bf(v.z); o.w = f2bf(v.w);
        *reinterpret_cast<ushort4*>(out + i) = o;
    } else if (bid < 17408) {
        const int local = bid - 12288;
        const int z = local >> 10;
        const int rem = local & 1023;
        const int i0 = (rem >> 5) * 32;
        const int j0 = (rem & 31) * 32;
        const float* in; us* out;
        switch (z) {
            case 0: in = Wq; out = Wqkv_t; break;
            case 1: in = Wk; out = Wqkv_t + 1024 * 1024; break;
            case 2: in = Wv; out = Wqkv_t + 2048 * 1024; break;
            case 3: in = Wr; out = Wr_t; break;
            default: in = Wo; out = Wo_t; break;
        }
        tr_core(t, in, out, 1024, 1024, i0, j0);
    } else {
        const int local = bid - 17408;
        if (local < 4096) {
            const int xb = local & 127, yb = local >> 7;
            tr_core(t, Wi, Wi_t, 1024, 4096, yb * 32, xb * 32);
        } else {
            const int l2 = local - 4096;
            const int xb = l2 & 127, yb = l2 >> 7;
            tr_core(t, Wout, Wout_t, 4096, 1024, xb * 32, yb * 32);
        }
    }
}

// ---------------------------------------------------------------------------
// Per-(b,n) transpose of V: v16 (stride ld) [B,S,*] -> vT16 [B,N,H,S] bf16.
// ---------------------------------------------------------------------------
__global__ __launch_bounds__(256) void transpose_v(
    const us* __restrict__ v16, us* __restrict__ vT16, int ld)
{
    __shared__ us T[64][72];
    const int s0 = blockIdx.x * 64;
    const int bn = blockIdx.y;          // b*16 + n
    const int b  = bn >> 4, n = bn & 15;
    const int t  = threadIdx.x;
    {
        const int r = t >> 2, c = (t & 3) * 16;
        const uint4* src = (const uint4*)(v16 + (size_t)(b * Ss + s0 + r) * ld + n * 64 + c);
        *(uint4*)&T[r][c]     = src[0];
        *(uint4*)&T[r][c + 8] = src[1];
    }
    __syncthreads();
    {
        const int h = t >> 2, c2 = (t & 3) * 16;
        us tmp[16];
        #pragma unroll
        for (int u = 0; u < 16; ++u) tmp[u] = T[c2 + u][h];
        us* dst = vT16 + (size_t)(bn * 64 + h) * Ss + s0 + c2;
        *(uint4*)dst       = *(uint4*)tmp;
        *(uint4*)(dst + 8) = *(uint4*)(tmp + 8);
    }
}

// ---------------------------------------------------------------------------
// bf16 MFMA GEMM body: C = A[M,K] @ B^T (B as [N][K]).
// Tile: (MT*32) x 128, BK=64, 4 waves 2x2; XOR-swizzled LDS (see R6/R7).
// ---------------------------------------------------------------------------
template<int MT, int OUT_BF16, int BIAS, int RELU>
static __device__ __forceinline__ void gemm_body(
    us* __restrict__ Asm, us* __restrict__ Bsm,
    const us* __restrict__ A, const us* __restrict__ B,
    const float* __restrict__ bias, void* __restrict__ Cv,
    int K, int ldC, int row0, int col0)
{
    const int tid  = threadIdx.x;
    const int lane = tid & 63;
    const int wave = tid >> 6;
    const int wr   = wave >> 1, wc = wave & 1;
    const int lrow = lane & 15;
    const int lq   = lane >> 4;
    const int h3   = lrow & 7;

    v4f acc[MT][4];
    #pragma unroll
    for (int mt = 0; mt < MT; ++mt)
        #pragma unroll
        for (int nt = 0; nt < 4; ++nt)
            acc[mt][nt] = (v4f){0.f, 0.f, 0.f, 0.f};

    for (int k0 = 0; k0 < K; k0 += 64) {
        #pragma unroll
        for (int u = 0; u < MT; ++u) {
            const int slot = u * 256 + tid;
            const int sr = slot >> 3;
            const int sc = ((slot & 7) ^ (sr & 7)) * 8;
            g2lds16(A + (size_t)(row0 + sr) * K + k0 + sc, &Asm[slot * 8]);
        }
        #pragma unroll
        for (int u = 0; u < 4; ++u) {
            const int slot = u * 256 + tid;
            const int sr = slot >> 3;
            const int sc = ((slot & 7) ^ (sr & 7)) * 8;
            g2lds16(B + (size_t)(col0 + sr) * K + k0 + sc, &Bsm[slot * 8]);
        }
        __syncthreads();

        #pragma unroll
        for (int t = 0; t < 2; ++t) {
            const int cc = ((lq + 4 * t) ^ h3) * 8;
            v8s af[MT], bf[4];
            #pragma unroll
            for (int mt = 0; mt < MT; ++mt)
                af[mt] = *reinterpret_cast<const v8s*>(
                    &Asm[(wr * (MT * 16) + mt * 16 + lrow) * 64 + cc]);
            #pragma unroll
            for (int nt = 0; nt < 4; ++nt)
                bf[nt] = *reinterpret_cast<const v8s*>(
                    &Bsm[(wc * 64 + nt * 16 + lrow) * 64 + cc]);
            #pragma unroll
            for (int mt = 0; mt < MT; ++mt)
                #pragma unroll
                for (int nt = 0; nt < 4; ++nt)
                    acc[mt][nt] = __builtin_amdgcn_mfma_f32_16x16x32_bf16(
                        af[mt], bf[nt], acc[mt][nt], 0, 0, 0);
        }
        __syncthreads();
    }

    #pragma unroll
    for (int nt = 0; nt < 4; ++nt) {
        const int col = col0 + wc * 64 + nt * 16 + lrow;
        const float bv = BIAS ? bias[col] : 0.f;
        #pragma unroll
        for (int mt = 0; mt < MT; ++mt) {
            #pragma unroll
            for (int v = 0; v < 4; ++v) {
                const int row = row0 + wr * (MT * 16) + mt * 16 + lq * 4 + v;
                float val = acc[mt][nt][v] + bv;
                if (RELU) val = fmaxf(val, 0.f);
                if (OUT_BF16)
                    ((us*)Cv)[(size_t)row * ldC + col] = f2bf(val);
                else
                    ((float*)Cv)[(size_t)row * ldC + col] = val;
            }
        }
    }
}

template<int MT, int OUT_BF16, int BIAS, int RELU>
__global__ __launch_bounds__(256) void gemm_tile(
    const us* __restrict__ A, const us* __restrict__ B,
    const float* __restrict__ bias, void* __restrict__ Cv,
    int K, int ldC)
{
    __shared__ us Asm[MT * 32 * 64];
    __shared__ us Bsm[128 * 64];
    gemm_body<MT, OUT_BF16, BIAS, RELU>(Asm, Bsm, A, B, bias, Cv, K, ldC,
                                        blockIdx.y * (MT * 32), blockIdx.x * 128);
}

// Fused QKV (768 blocks) + R (512 blocks) projection in one 1280-block launch.
__global__ __launch_bounds__(256) void gemm_qkv_r(
    const us* __restrict__ x16, const us* __restrict__ Wqkv,
    us* __restrict__ qkv, const us* __restrict__ rpe16,
    const us* __restrict__ Wr, us* __restrict__ rout)
{
    __shared__ us Asm[128 * 64];
    __shared__ us Bsm[128 * 64];
    const int bid = blockIdx.x;
    if (bid < 768) {
        gemm_body<4,1,0,0>(Asm, Bsm, x16, Wqkv, nullptr, qkv, Ee, QKVLD,
                           (bid / 24) * 128, (bid % 24) * 128);
    } else {
        const int b2 = bid - 768;
        gemm_body<4,1,0,0>(Asm, Bsm, rpe16, Wr, nullptr, rout, Ee, NHh,
                           (b2 / 8) * 128, (b2 % 8) * 128);
    }
}

// ---------------------------------------------------------------------------
// MFMA flash attention with rel-shift ring buffer.
// R12: restore R10 verbatim (measured 73.4 us). R11's 4-resident variant with
// direct-global V tripled L2 traffic (FETCH 23.5->63.8 MB, WRITE 8.2->26.6 MB)
// and doubled the time: at 4 blocks/CU the per-XCD working set exceeds the
// 4 MB L2 unless ALL operands are staged through LDS. This is the staged
// structure: Kt/Rt/VtT 16B-granule XOR swizzle, row-XOR ring, Pt overlay on
// Kt (B3 barrier), reg-built q-frags, exp2f, setprio on PV. LDS 40960 -> 3
// blocks/CU resident (residency tail accepted; 4-resident requires an
// all-staged 32 KB layout, a future candidate).
// ---------------------------------------------------------------------------
__global__ __launch_bounds__(256, 4) void attn_mfma(
    const us* __restrict__ qkv, const us* __restrict__ vT16,
    const us* __restrict__ r16,
    const float* __restrict__ cb, const float* __restrict__ pb,
    us* __restrict__ attn)
{
    __shared__ __align__(16) us smem[20480];    // 40960 B
    us* Kt   = smem;            // 64 x 64 swz (8192 B); overlaid by Pt
    us* Rt   = smem + 4096;     // 64 x 64 swz
    us* VtT  = smem + 8192;     // 64 x 64 swz
    us* ring = smem + 12288;    // 128 cols x 64 rows, row-XOR swz (16384 B)
    us* Pt   = Kt;              // overlay

    const int bn = blockIdx.x;         // b*16 + n  (XCD = bn & 7)
    const int b  = bn >> 4;
    const int n  = bn & 15;
    const int i0 = blockIdx.y * 64;
    const int tid  = threadIdx.x;
    const int lane = tid & 63;
    const int w    = tid >> 6;
    const int quad = lane >> 4;
    const int l15  = lane & 15;
    const int l7   = l15 & 7;
    const int w16  = w * 16;

    const float SCALE = 0.125f * 1.44269504088896f;   // 1/sqrt(H) * log2(e)

    // ---- Prologue: A-fragments qc/qp built per-lane direct from global ----
    v8s aqc0, aqc1, aqp0, aqp1;
    {
        const us* qrow = qkv + (size_t)(b * Ss + i0 + w16 + l15) * QKVLD + n * 64;
        const v8s q0 = *(const v8s*)(qrow + quad * 8);
        const v8s q1 = *(const v8s*)(qrow + 32 + quad * 8);
        const float* cbp = cb + n * 64 + quad * 8;
        const float* pbp = pb + n * 64 + quad * 8;
        #pragma unroll
        for (int u = 0; u < 8; ++u) {
            const float f0 = bf2f((us)q0[u]);
            const float f1 = bf2f((us)q1[u]);
            aqc0[u] = (short)f2bf((f0 + cbp[u])      * SCALE);
            aqc1[u] = (short)f2bf((f1 + cbp[u + 32]) * SCALE);
            aqp0[u] = (short)f2bf((f0 + pbp[u])      * SCALE);
            aqp1[u] = (short)f2bf((f1 + pbp[u + 32]) * SCALE);
        }
    }

    const int c0 = Ss - i0;   // l at j-i diag base

    // Staging geometry (shared by bootstrap + main loop)
    const int sgr = tid >> 2;            // row 0..63
    const int scg = (tid & 3) * 2;       // first 16B granule (0,2,4,6)
    const int srx = sgr & 7;
    us* const kd0 = &Kt [sgr * 64 + ((scg ^ srx) << 3)];
    us* const kd1 = &Kt [sgr * 64 + (((scg + 1) ^ srx) << 3)];
    us* const rd0 = &Rt [sgr * 64 + ((scg ^ srx) << 3)];
    us* const rd1 = &Rt [sgr * 64 + (((scg + 1) ^ srx) << 3)];
    us* const vd0 = &VtT[sgr * 64 + ((scg ^ srx) << 3)];
    us* const vd1 = &VtT[sgr * 64 + (((scg + 1) ^ srx) << 3)];

    // ---- Bootstrap: pos chunk l in [c0-64, c0) -> ring cols j in [irow-i0-64, irow-i0) ----
    {
        const uint4* sr = (const uint4*)(r16 + (size_t)(b * Rr + (c0 - 64) + sgr) * NHh + n * 64 + scg * 8);
        uint4 r0v = sr[0], r1v = sr[1];
        *(uint4*)rd0 = r0v;
        *(uint4*)rd1 = r1v;
        __syncthreads();
        const v4f z = (v4f){0.f, 0.f, 0.f, 0.f};
        #pragma unroll
        for (int t = 0; t < 4; ++t) {
            const int row = t * 16 + l15;
            v8s br0 = *(const v8s*)&Rt[row * 64 + ((quad ^ l7) << 3)];
            v8s br1 = *(const v8s*)&Rt[row * 64 + (((quad + 4) ^ l7) << 3)];
            v4f pp = __builtin_amdgcn_mfma_f32_16x16x32_bf16(aqp0, br0, z, 0, 0, 0);
            pp = __builtin_amdgcn_mfma_f32_16x16x32_bf16(aqp1, br1, pp, 0, 0, 0);
            const int colbase = t * 16 + l15 - 64;   // j = colbase + irow
            #pragma unroll
            for (int v = 0; v < 4; ++v) {
                const int irow = w16 + quad * 4 + v;
                const int col = (colbase + irow) & 127;
                ring[col * 64 + (irow ^ ((col & 7) << 3))] = f2bf(pp[v]);
            }
        }
    }

    v4f Oa[4];
    #pragma unroll
    for (int t = 0; t < 4; ++t) Oa[t] = (v4f){0.f, 0.f, 0.f, 0.f};
    float la[4] = {0.f, 0.f, 0.f, 0.f};

    // ---- Main flash loop over key tiles ----
    for (int j0 = 0; j0 < Ss; j0 += 64) {
        __syncthreads();   // B1: prev iter Pt/VtT/bootstrap Rt reads done
        {
            const uint4* sk = (const uint4*)(qkv + (size_t)(b * Ss + j0 + sgr) * QKVLD + NHh + n * 64 + scg * 8);
            const uint4* sr = (const uint4*)(r16 + (size_t)(b * Rr + (j0 + c0) + sgr) * NHh + n * 64 + scg * 8);
            const uint4* sv = (const uint4*)(vT16 + (size_t)(bn * 64 + sgr) * Ss + j0 + scg * 8);
            uint4 k0v = sk[0], k1v = sk[1];
            uint4 r0v = sr[0], r1v = sr[1];
            uint4 v0v = sv[0], v1v = sv[1];
            *(uint4*)kd0 = k0v;  *(uint4*)kd1 = k1v;
            *(uint4*)rd0 = r0v;  *(uint4*)rd1 = r1v;
            *(uint4*)vd0 = v0v;  *(uint4*)vd1 = v1v;
        }
        __syncthreads();   // B2: stage visible

        const v4f z = (v4f){0.f, 0.f, 0.f, 0.f};
        // Content scores
        v4f sc[4];
        #pragma unroll
        for (int t = 0; t < 4; ++t) {
            const int row = t * 16 + l15;
            v8s bk0 = *(const v8s*)&Kt[row * 64 + ((quad ^ l7) << 3)];
            v8s bk1 = *(const v8s*)&Kt[row * 64 + (((quad + 4) ^ l7) << 3)];
            sc[t] = __builtin_amdgcn_mfma_f32_16x16x32_bf16(aqc0, bk0, z, 0, 0, 0);
            sc[t] = __builtin_amdgcn_mfma_f32_16x16x32_bf16(aqc1, bk1, sc[t], 0, 0, 0);
        }
        // Pos chunk -> ring (skewed cm: col = j & 127, row-XOR swizzle)
        #pragma unroll
        for (int t = 0; t < 4; ++t) {
            const int row = t * 16 + l15;
            v8s br0 = *(const v8s*)&Rt[row * 64 + ((quad ^ l7) << 3)];
            v8s br1 = *(const v8s*)&Rt[row * 64 + (((quad + 4) ^ l7) << 3)];
            v4f pp = __builtin_amdgcn_mfma_f32_16x16x32_bf16(aqp0, br0, z, 0, 0, 0);
            pp = __builtin_amdgcn_mfma_f32_16x16x32_bf16(aqp1, br1, pp, 0, 0, 0);
            const int colbase = j0 + t * 16 + l15;
            #pragma unroll
            for (int v = 0; v < 4; ++v) {
                const int irow = w16 + quad * 4 + v;
                const int col = (colbase + irow) & 127;
                ring[col * 64 + (irow ^ ((col & 7) << 3))] = f2bf(pp[v]);
            }
        }

        __syncthreads();   // B3: all waves' Kt reads done -> Pt may overwrite

        // Scores -> exp2 -> Pt (=Kt); pos gathered via one b64 per t
        #pragma unroll
        for (int t = 0; t < 4; ++t) {
            const int col = (j0 + t * 16 + l15) & 127;
            const int rbase = (w16 + quad * 4) ^ ((col & 7) << 3);
            const v4us pr = *(const v4us*)&ring[col * 64 + rbase];
            const int j = t * 16 + l15;
            const int gsw = j >> 3;            // 2t + (l15>>3)
            #pragma unroll
            for (int v = 0; v < 4; ++v) {
                const int irow = w16 + quad * 4 + v;
                const float p = exp2f(sc[t][v] + bf2f(pr[v]));
                la[v] += p;
                Pt[irow * 64 + (((gsw ^ (irow & 7)) << 3) | (j & 7))] = f2bf(p);
            }
        }

        // PV
        v8s pa0 = *(v8s*)&Pt[(w16 + l15) * 64 + ((quad ^ l7) << 3)];
        v8s pa1 = *(v8s*)&Pt[(w16 + l15) * 64 + (((quad + 4) ^ l7) << 3)];
        __builtin_amdgcn_s_setprio(1);
        #pragma unroll
        for (int ht = 0; ht < 4; ++ht) {
            const int row = ht * 16 + l15;
            v8s bv0 = *(const v8s*)&VtT[row * 64 + ((quad ^ l7) << 3)];
            v8s bv1 = *(const v8s*)&VtT[row * 64 + (((quad + 4) ^ l7) << 3)];
            Oa[ht] = __builtin_amdgcn_mfma_f32_16x16x32_bf16(pa0, bv0, Oa[ht], 0, 0, 0);
            Oa[ht] = __builtin_amdgcn_mfma_f32_16x16x32_bf16(pa1, bv1, Oa[ht], 0, 0, 0);
        }
        __builtin_amdgcn_s_setprio(0);
    }

    // ---- Epilogue: reduce row sums across quad, normalize, store ----
    #pragma unroll
    for (int v = 0; v < 4; ++v) {
        la[v] += __shfl_xor(la[v], 1);
        la[v] += __shfl_xor(la[v], 2);
        la[v] += __shfl_xor(la[v], 4);
        la[v] += __shfl_xor(la[v], 8);
        la[v] = 1.f / la[v];
    }
    #pragma unroll
    for (int ht = 0; ht < 4; ++ht) {
        #pragma unroll
        for (int v = 0; v < 4; ++v) {
            const int irow = w16 + quad * 4 + v;
            attn[(size_t)(b * Ss + i0 + irow) * NHh + n * 64 + ht * 16 + l15] =
                f2bf(Oa[ht][v] * la[v]);
        }
    }
}

// ---------------------------------------------------------------------------
// Fused residual-add + LayerNorm over E=1024; optional bf16 copy of output.
// R12: float4/ushort4 vectorized (G13) — 16 B/lane loads and stores.
// Each thread owns 4 contiguous elements (idx = tid*4).
// ---------------------------------------------------------------------------
template<int W16>
__global__ __launch_bounds__(256) void add_ln_kernel(
    const float* __restrict__ a, const float* __restrict__ res,
    const float* __restrict__ g, const float* __restrict__ bet,
    float* __restrict__ out, us* __restrict__ out16)
{
    const int row = blockIdx.x;
    const int tid = threadIdx.x;
    const int idx = tid * 4;
    const float4 va = *reinterpret_cast<const float4*>(a   + (size_t)row * Ee + idx);
    const float4 vr = *reinterpret_cast<const float4*>(res + (size_t)row * Ee + idx);

    float vals[4];
    vals[0] = va.x + vr.x; vals[1] = va.y + vr.y;
    vals[2] = va.z + vr.z; vals[3] = va.w + vr.w;
    float lsum = 0.f, lsq = 0.f;
    #pragma unroll
    for (int it = 0; it < 4; ++it) {
        lsum += vals[it];
        lsq  = fmaf(vals[it], vals[it], lsq);
    }
    #pragma unroll
    for (int off = 32; off > 0; off >>= 1) {
        lsum += __shfl_down(lsum, off);
        lsq  += __shfl_down(lsq,  off);
    }
    __shared__ float w1[4], w2[4];
    if ((tid & 63) == 0) { w1[tid >> 6] = lsum; w2[tid >> 6] = lsq; }
    __syncthreads();
    const float sum  = w1[0] + w1[1] + w1[2] + w1[3];
    const float sq   = w2[0] + w2[1] + w2[2] + w2[3];
    const float mean = sum * (1.f / 1024.f);
    const float var  = sq * (1.f / 1024.f) - mean * mean;
    const float rstd = rsqrtf(var + 1e-12f);

    const float4 vg = *reinterpret_cast<const float4*>(g   + idx);
    const float4 vb = *reinterpret_cast<const float4*>(bet + idx);
    float4 o;
    o.x = (vals[0] - mean) * rstd * vg.x + vb.x;
    o.y = (vals[1] - mean) * rstd * vg.y + vb.y;
    o.z = (vals[2] - mean) * rstd * vg.z + vb.z;
    o.w = (vals[3] - mean) * rstd * vg.w + vb.w;
    *reinterpret_cast<float4*>(out + (size_t)row * Ee + idx) = o;
    if (W16) {
        ushort4 o16;
        o16.x = f2bf(o.x); o16.y = f2bf(o.y);
        o16.z = f2bf(o.z); o16.w = f2bf(o.w);
        *reinterpret_cast<ushort4*>(out16 + (size_t)row * Ee + idx) = o16;
    }
}

// ---------------------------------------------------------------------------
// Orchestration. Workspace layout (1 MB units), 90 MB total:
//   [ 0, 8)  x16      -> attn16 (ph3)  -> inner16 head (ph6)
//   [ 8,24)  rpe16    -> vT16 [8,16) (ph2.5), ao fp32 [16,24) (ph4)
//   [24,30)  Wqkv_t   [30,32) Wr_t   [32,34) Wo_t      (inner16 covers 0..32)
//   [34,42)  Wi_t     [42,50) Wout_t
//   [50,74)  qkv16    -> h16 [50,58) + hb fp32 [58,74) (ph5)
//   [74,90)  r16      -> out2 fp32 (ph7)
// ---------------------------------------------------------------------------
#define MB (1u << 20)

extern "C" void kernel_launch(void* const* d_in, const int* in_sizes, int n_in,
                              void* d_out, int out_size, void* d_ws, size_t ws_size,
                              hipStream_t stream)
{
    (void)in_sizes; (void)n_in; (void)out_size; (void)ws_size;

    const float* x    = (const float*)d_in[0];
    const float* cbf  = (const float*)d_in[1];
    const float* pbf  = (const float*)d_in[2];
    const float* rpe  = (const float*)d_in[3];
    const float* Wq   = (const float*)d_in[4];
    const float* Wk   = (const float*)d_in[5];
    const float* Wv   = (const float*)d_in[6];
    const float* Wr   = (const float*)d_in[7];
    const float* Wo   = (const float*)d_in[8];
    const float* ln1g = (const float*)d_in[9];
    const float* ln1b = (const float*)d_in[10];
    const float* Wi   = (const float*)d_in[11];
    const float* bi   = (const float*)d_in[12];
    const float* Wout = (const float*)d_in[13];
    const float* bout = (const float*)d_in[14];
    const float* ln2g = (const float*)d_in[15];
    const float* ln2b = (const float*)d_in[16];

    float* out = (float*)d_out;
    char*  ws  = (char*)d_ws;

    us* x16    = (us*)(ws + 0 * MB);
    us* rpe16  = (us*)(ws + 8 * MB);
    us* Wqkv_t = (us*)(ws + 24 * MB);           // [3072][1024]
    us* Wr_t   = (us*)(ws + 30 * MB);
    us* Wo_t   = (us*)(ws + 32 * MB);
    us* Wi_t   = (us*)(ws + 34 * MB);
    us* Wout_t = (us*)(ws + 42 * MB);
    us* qkv16  = (us*)(ws + 50 * MB);           // [BS][3072]
    us* r16    = (us*)(ws + 74 * MB);
    us* vT16   = (us*)(ws + 8 * MB);            // reuse rpe16 (after qkv_r gemm)
    us* attn16 = (us*)(ws + 0 * MB);            // reuse x16
    float* ao  = (float*)(ws + 16 * MB);        // [16,24)
    us* h16    = (us*)(ws + 50 * MB);           // reuse qkv16
    float* hb  = (float*)(ws + 58 * MB);        // reuse qkv16 tail
    us* inner16= (us*)(ws + 0 * MB);            // 0..32 MB
    float* out2= (float*)(ws + 74 * MB);        // reuse r16

    const dim3 blk(256);

    // Phase 1: all converts + transposes, one dispatch
    prep_all<<<dim3(25600), blk, 0, stream>>>(
        x, x16, rpe, rpe16, Wq, Wk, Wv, Wr, Wo,
        Wqkv_t, Wr_t, Wo_t, Wi, Wi_t, Wout, Wout_t);

    // Phase 2: fused QKV + R projection (one 1280-block dispatch)
    gemm_qkv_r<<<dim3(1280), blk, 0, stream>>>(x16, Wqkv_t, qkv16, rpe16, Wr_t, r16);

    // Phase 2.5: V transpose (v cols of qkv) -> [B,N,H,S]
    transpose_v<<<dim3(16, 64), blk, 0, stream>>>(qkv16 + 2048, vT16, QKVLD);

    // Phase 3: MFMA flash attention; grid (bn, i) for XCD-local K/R/V reuse
    attn_mfma<<<dim3(64, 16), blk, 0, stream>>>(qkv16, vT16, r16, cbf, pbf, attn16);

    // Phase 4: output projection (fp32 out), 64-row tiles -> 512 blocks (2/CU)
    gemm_tile<2,0,0,0><<<dim3(8, 64), blk, 0, stream>>>(attn16, Wo_t, nullptr, ao, NHh, Ee);

    // Phase 5: h = LN1(ao + x), fp32 + bf16
    add_ln_kernel<1><<<dim3(BSs), blk, 0, stream>>>(ao, x, ln1g, ln1b, hb, h16);

    // Phase 6: FFN1 (bias+relu, bf16 out), 128-row tiles, 1024 blocks
    gemm_tile<4,1,1,1><<<dim3(32, 32), blk, 0, stream>>>(h16, Wi_t, bi, inner16, Ee, Ff);

    // Phase 7: FFN2 (bias, fp32 out), 64-row tiles -> 512 blocks (2+/CU)
    gemm_tile<2,0,1,0><<<dim3(8, 64), blk, 0, stream>>>(inner16, Wout_t, bout, out2, Ff, Ee);

    // Phase 8: out = LN2(out2 + h)
    add_ln_kernel<0><<<dim3(BSs), blk, 0, stream>>>(out2, hb, ln2g, ln2b, out, nullptr);
}

// Round 5
// 418.404 us; speedup vs baseline: 1.2071x; 1.0335x over previous
//
#include <hip/hip_runtime.h>
#include <math.h>

// Problem constants
#define Bb   4
#define Ss   1024
#define Ee   1024
#define Nn   16
#define Hh   64
#define Ff   4096
#define Rr   2048
#define NHh  1024   // N*H
#define BSs  4096   // B*S
#define QKVLD 3072  // fused qkv row stride

typedef short v8s __attribute__((ext_vector_type(8)));
typedef float v4f __attribute__((ext_vector_type(4)));
typedef unsigned short v4us __attribute__((ext_vector_type(4)));
typedef unsigned int u32;
typedef unsigned short us;

static __device__ inline us f2bf(float f) {
    u32 u = __builtin_bit_cast(u32, f);
    u += 0x7fffu + ((u >> 16) & 1u);   // RNE
    return (us)(u >> 16);
}
static __device__ inline float bf2f(us h) {
    u32 u = ((u32)h) << 16;
    return __builtin_bit_cast(float, u);
}
static __device__ inline void g2lds16(const void* g, void* l) {
    __builtin_amdgcn_global_load_lds(
        (const __attribute__((address_space(1))) u32*)g,
        (__attribute__((address_space(3))) u32*)l, 16, 0, 0);
}

// ---------------------------------------------------------------------------
// Transpose + cvt core: in [K][N] fp32 -> out [N][K] bf16, 32x32 tile.
// ---------------------------------------------------------------------------
static __device__ __forceinline__ void tr_core(
    float (*t)[33],
    const float* __restrict__ in, us* __restrict__ out,
    int K, int N, int i0, int j0)
{
    const int r  = threadIdx.x >> 3;
    const int c4 = (threadIdx.x & 7) * 4;
    const float4 v = *reinterpret_cast<const float4*>(in + (size_t)(i0 + r) * N + j0 + c4);
    t[r][c4 + 0] = v.x; t[r][c4 + 1] = v.y; t[r][c4 + 2] = v.z; t[r][c4 + 3] = v.w;
    __syncthreads();
    ushort4 o;
    o.x = f2bf(t[c4 + 0][r]); o.y = f2bf(t[c4 + 1][r]);
    o.z = f2bf(t[c4 + 2][r]); o.w = f2bf(t[c4 + 3][r]);
    *reinterpret_cast<ushort4*>(out + (size_t)(j0 + r) * K + i0 + c4) = o;
}

// ---------------------------------------------------------------------------
// One merged prep kernel: x/rpe cvt (blocks [0,12288)), 5 square weight
// transposes ([12288,17408)), Wi/Wout transposes ([17408,25600)).
// ---------------------------------------------------------------------------
__global__ __launch_bounds__(256) void prep_all(
    const float* __restrict__ x, us* __restrict__ x16,
    const float* __restrict__ rpe, us* __restrict__ rpe16,
    const float* __restrict__ Wq, const float* __restrict__ Wk,
    const float* __restrict__ Wv, const float* __restrict__ Wr,
    const float* __restrict__ Wo,
    us* __restrict__ Wqkv_t, us* __restrict__ Wr_t, us* __restrict__ Wo_t,
    const float* __restrict__ Wi, us* __restrict__ Wi_t,
    const float* __restrict__ Wout, us* __restrict__ Wout_t)
{
    __shared__ float t[32][33];
    const int bid = blockIdx.x;
    if (bid < 12288) {
        const float* in; us* out; size_t base;
        if (bid < 4096) { in = x; out = x16; base = (size_t)bid; }
        else { in = rpe; out = rpe16; base = (size_t)(bid - 4096); }
        const size_t i = (base * 256 + threadIdx.x) * 4;
        const float4 v = *reinterpret_cast<const float4*>(in + i);
        ushort4 o;
        o.x = f2bf(v.x); o.y = f2bf(v.y); o.z = f2bf(v.z); o.w = f2bf(v.w);
        *reinterpret_cast<ushort4*>(out + i) = o;
    } else if (bid < 17408) {
        const int local = bid - 12288;
        const int z = local >> 10;
        const int rem = local & 1023;
        const int i0 = (rem >> 5) * 32;
        const int j0 = (rem & 31) * 32;
        const float* in; us* out;
        switch (z) {
            case 0: in = Wq; out = Wqkv_t; break;
            case 1: in = Wk; out = Wqkv_t + 1024 * 1024; break;
            case 2: in = Wv; out = Wqkv_t + 2048 * 1024; break;
            case 3: in = Wr; out = Wr_t; break;
            default: in = Wo; out = Wo_t; break;
        }
        tr_core(t, in, out, 1024, 1024, i0, j0);
    } else {
        const int local = bid - 17408;
        if (local < 4096) {
            const int xb = local & 127, yb = local >> 7;
            tr_core(t, Wi, Wi_t, 1024, 4096, yb * 32, xb * 32);
        } else {
            const int l2 = local - 4096;
            const int xb = l2 & 127, yb = l2 >> 7;
            tr_core(t, Wout, Wout_t, 4096, 1024, xb * 32, yb * 32);
        }
    }
}

// ---------------------------------------------------------------------------
// Per-(b,n) transpose of V: v16 (stride ld) [B,S,*] -> vT16 [B,N,H,S] bf16.
// ---------------------------------------------------------------------------
__global__ __launch_bounds__(256) void transpose_v(
    const us* __restrict__ v16, us* __restrict__ vT16, int ld)
{
    __shared__ us T[64][72];
    const int s0 = blockIdx.x * 64;
    const int bn = blockIdx.y;          // b*16 + n
    const int b  = bn >> 4, n = bn & 15;
    const int t  = threadIdx.x;
    {
        const int r = t >> 2, c = (t & 3) * 16;
        const uint4* src = (const uint4*)(v16 + (size_t)(b * Ss + s0 + r) * ld + n * 64 + c);
        *(uint4*)&T[r][c]     = src[0];
        *(uint4*)&T[r][c + 8] = src[1];
    }
    __syncthreads();
    {
        const int h = t >> 2, c2 = (t & 3) * 16;
        us tmp[16];
        #pragma unroll
        for (int u = 0; u < 16; ++u) tmp[u] = T[c2 + u][h];
        us* dst = vT16 + (size_t)(bn * 64 + h) * Ss + s0 + c2;
        *(uint4*)dst       = *(uint4*)tmp;
        *(uint4*)(dst + 8) = *(uint4*)(tmp + 8);
    }
}

// ---------------------------------------------------------------------------
// bf16 MFMA GEMM body: C = A[M,K] @ B^T (B as [N][K]).
// Tile: (MT*32) x 128, BK=64, 4 waves 2x2; XOR-swizzled LDS (see R6/R7).
// ---------------------------------------------------------------------------
template<int MT, int OUT_BF16, int BIAS, int RELU>
static __device__ __forceinline__ void gemm_body(
    us* __restrict__ Asm, us* __restrict__ Bsm,
    const us* __restrict__ A, const us* __restrict__ B,
    const float* __restrict__ bias, void* __restrict__ Cv,
    int K, int ldC, int row0, int col0)
{
    const int tid  = threadIdx.x;
    const int lane = tid & 63;
    const int wave = tid >> 6;
    const int wr   = wave >> 1, wc = wave & 1;
    const int lrow = lane & 15;
    const int lq   = lane >> 4;
    const int h3   = lrow & 7;

    v4f acc[MT][4];
    #pragma unroll
    for (int mt = 0; mt < MT; ++mt)
        #pragma unroll
        for (int nt = 0; nt < 4; ++nt)
            acc[mt][nt] = (v4f){0.f, 0.f, 0.f, 0.f};

    for (int k0 = 0; k0 < K; k0 += 64) {
        #pragma unroll
        for (int u = 0; u < MT; ++u) {
            const int slot = u * 256 + tid;
            const int sr = slot >> 3;
            const int sc = ((slot & 7) ^ (sr & 7)) * 8;
            g2lds16(A + (size_t)(row0 + sr) * K + k0 + sc, &Asm[slot * 8]);
        }
        #pragma unroll
        for (int u = 0; u < 4; ++u) {
            const int slot = u * 256 + tid;
            const int sr = slot >> 3;
            const int sc = ((slot & 7) ^ (sr & 7)) * 8;
            g2lds16(B + (size_t)(col0 + sr) * K + k0 + sc, &Bsm[slot * 8]);
        }
        __syncthreads();

        #pragma unroll
        for (int t = 0; t < 2; ++t) {
            const int cc = ((lq + 4 * t) ^ h3) * 8;
            v8s af[MT], bf[4];
            #pragma unroll
            for (int mt = 0; mt < MT; ++mt)
                af[mt] = *reinterpret_cast<const v8s*>(
                    &Asm[(wr * (MT * 16) + mt * 16 + lrow) * 64 + cc]);
            #pragma unroll
            for (int nt = 0; nt < 4; ++nt)
                bf[nt] = *reinterpret_cast<const v8s*>(
                    &Bsm[(wc * 64 + nt * 16 + lrow) * 64 + cc]);
            #pragma unroll
            for (int mt = 0; mt < MT; ++mt)
                #pragma unroll
                for (int nt = 0; nt < 4; ++nt)
                    acc[mt][nt] = __builtin_amdgcn_mfma_f32_16x16x32_bf16(
                        af[mt], bf[nt], acc[mt][nt], 0, 0, 0);
        }
        __syncthreads();
    }

    #pragma unroll
    for (int nt = 0; nt < 4; ++nt) {
        const int col = col0 + wc * 64 + nt * 16 + lrow;
        const float bv = BIAS ? bias[col] : 0.f;
        #pragma unroll
        for (int mt = 0; mt < MT; ++mt) {
            #pragma unroll
            for (int v = 0; v < 4; ++v) {
                const int row = row0 + wr * (MT * 16) + mt * 16 + lq * 4 + v;
                float val = acc[mt][nt][v] + bv;
                if (RELU) val = fmaxf(val, 0.f);
                if (OUT_BF16)
                    ((us*)Cv)[(size_t)row * ldC + col] = f2bf(val);
                else
                    ((float*)Cv)[(size_t)row * ldC + col] = val;
            }
        }
    }
}

// R13: bijective XCD-aware block swizzle (T1). All grids have nwg % 8 == 0.
// Blocks with the same (flat % 8) land on the same XCD; remapping them to a
// CONTIGUOUS tile range makes same-XCD blocks share A row-panels in that
// XCD's L2 (linear dispatch spread panel-sharing neighbors across XCDs).
template<int MT, int OUT_BF16, int BIAS, int RELU>
__global__ __launch_bounds__(256) void gemm_tile(
    const us* __restrict__ A, const us* __restrict__ B,
    const float* __restrict__ bias, void* __restrict__ Cv,
    int K, int ldC)
{
    __shared__ us Asm[MT * 32 * 64];
    __shared__ us Bsm[128 * 64];
    const int gx  = gridDim.x;
    const int nwg = gx * gridDim.y;
    int flat = blockIdx.y * gx + blockIdx.x;
    flat = (flat & 7) * (nwg >> 3) + (flat >> 3);
    const int by = flat / gx, bx = flat - by * gx;
    gemm_body<MT, OUT_BF16, BIAS, RELU>(Asm, Bsm, A, B, bias, Cv, K, ldC,
                                        by * (MT * 32), bx * 128);
}

// Fused QKV (768 blocks) + R (512 blocks) projection in one 1280-block launch.
// R13: per-section XCD swizzle (768%8==0, 512%8==0, and (bid-768)%8==bid%8).
__global__ __launch_bounds__(256) void gemm_qkv_r(
    const us* __restrict__ x16, const us* __restrict__ Wqkv,
    us* __restrict__ qkv, const us* __restrict__ rpe16,
    const us* __restrict__ Wr, us* __restrict__ rout)
{
    __shared__ us Asm[128 * 64];
    __shared__ us Bsm[128 * 64];
    const int bid = blockIdx.x;
    if (bid < 768) {
        const int o = (bid & 7) * 96 + (bid >> 3);
        gemm_body<4,1,0,0>(Asm, Bsm, x16, Wqkv, nullptr, qkv, Ee, QKVLD,
                           (o / 24) * 128, (o % 24) * 128);
    } else {
        const int b2 = bid - 768;
        const int o = (b2 & 7) * 64 + (b2 >> 3);
        gemm_body<4,1,0,0>(Asm, Bsm, rpe16, Wr, nullptr, rout, Ee, NHh,
                           (o / 8) * 128, (o % 8) * 128);
    }
}

// ---------------------------------------------------------------------------
// MFMA flash attention with rel-shift ring buffer.
// R13: 4-resident all-staged. R11/R12 established: 32768 B LDS -> 4 blocks/CU
// (no residency tail), but direct-global V blows L2 (R11). Fix: time-share
// the Rt buffer. R is read only in the QK/pos phase; V only in PV. V is
// loaded to REGISTERS in the same stage block as K/R (loads complete
// together by B2 - no new exposed latency), then ds_written into Rt AFTER
// B3 (all Rt reads done), with a new B4 before PV. Same global traffic as
// R10/R12 (FETCH ~23.5 MB), R11's residency.
// Layout: Kt 8KB (Pt overlay) | Rt 8KB (V overlay) | ring 16KB = 32768 B.
// Barriers/iter: B1 (prev PV reads done) -> stage K,R; B2 -> QK+pos;
// B3 -> V->Rt, softmax->Pt; B4 -> PV.
// ---------------------------------------------------------------------------
__global__ __launch_bounds__(256, 4) void attn_mfma(
    const us* __restrict__ qkv, const us* __restrict__ vT16,
    const us* __restrict__ r16,
    const float* __restrict__ cb, const float* __restrict__ pb,
    us* __restrict__ attn)
{
    __shared__ __align__(16) us smem[16384];    // 32768 B
    us* Kt   = smem;            // 64 x 64 swz (8192 B); overlaid by Pt
    us* Rt   = smem + 4096;     // 64 x 64 swz (8192 B); overlaid by V
    us* ring = smem + 8192;     // 128 cols x 64 rows, row-XOR swz (16384 B)
    us* Pt   = Kt;              // overlay

    const int bn = blockIdx.x;         // b*16 + n  (XCD = bn & 7)
    const int b  = bn >> 4;
    const int n  = bn & 15;
    const int i0 = blockIdx.y * 64;
    const int tid  = threadIdx.x;
    const int lane = tid & 63;
    const int w    = tid >> 6;
    const int quad = lane >> 4;
    const int l15  = lane & 15;
    const int l7   = l15 & 7;
    const int w16  = w * 16;

    const float SCALE = 0.125f * 1.44269504088896f;   // 1/sqrt(H) * log2(e)

    // ---- Prologue: A-fragments qc/qp built per-lane direct from global ----
    v8s aqc0, aqc1, aqp0, aqp1;
    {
        const us* qrow = qkv + (size_t)(b * Ss + i0 + w16 + l15) * QKVLD + n * 64;
        const v8s q0 = *(const v8s*)(qrow + quad * 8);
        const v8s q1 = *(const v8s*)(qrow + 32 + quad * 8);
        const float* cbp = cb + n * 64 + quad * 8;
        const float* pbp = pb + n * 64 + quad * 8;
        #pragma unroll
        for (int u = 0; u < 8; ++u) {
            const float f0 = bf2f((us)q0[u]);
            const float f1 = bf2f((us)q1[u]);
            aqc0[u] = (short)f2bf((f0 + cbp[u])      * SCALE);
            aqc1[u] = (short)f2bf((f1 + cbp[u + 32]) * SCALE);
            aqp0[u] = (short)f2bf((f0 + pbp[u])      * SCALE);
            aqp1[u] = (short)f2bf((f1 + pbp[u + 32]) * SCALE);
        }
    }

    const int c0 = Ss - i0;   // l at j-i diag base

    // Staging geometry (shared by bootstrap + main loop)
    const int sgr = tid >> 2;            // row 0..63
    const int scg = (tid & 3) * 2;       // first 16B granule (0,2,4,6)
    const int srx = sgr & 7;
    us* const kd0 = &Kt[sgr * 64 + ((scg ^ srx) << 3)];
    us* const kd1 = &Kt[sgr * 64 + (((scg + 1) ^ srx) << 3)];
    us* const rd0 = &Rt[sgr * 64 + ((scg ^ srx) << 3)];
    us* const rd1 = &Rt[sgr * 64 + (((scg + 1) ^ srx) << 3)];

    // ---- Bootstrap: pos chunk l in [c0-64, c0) -> ring cols j in [irow-i0-64, irow-i0) ----
    {
        const uint4* sr = (const uint4*)(r16 + (size_t)(b * Rr + (c0 - 64) + sgr) * NHh + n * 64 + scg * 8);
        uint4 r0v = sr[0], r1v = sr[1];
        *(uint4*)rd0 = r0v;
        *(uint4*)rd1 = r1v;
        __syncthreads();
        const v4f z = (v4f){0.f, 0.f, 0.f, 0.f};
        #pragma unroll
        for (int t = 0; t < 4; ++t) {
            const int row = t * 16 + l15;
            v8s br0 = *(const v8s*)&Rt[row * 64 + ((quad ^ l7) << 3)];
            v8s br1 = *(const v8s*)&Rt[row * 64 + (((quad + 4) ^ l7) << 3)];
            v4f pp = __builtin_amdgcn_mfma_f32_16x16x32_bf16(aqp0, br0, z, 0, 0, 0);
            pp = __builtin_amdgcn_mfma_f32_16x16x32_bf16(aqp1, br1, pp, 0, 0, 0);
            const int colbase = t * 16 + l15 - 64;   // j = colbase + irow
            #pragma unroll
            for (int v = 0; v < 4; ++v) {
                const int irow = w16 + quad * 4 + v;
                const int col = (colbase + irow) & 127;
                ring[col * 64 + (irow ^ ((col & 7) << 3))] = f2bf(pp[v]);
            }
        }
    }

    v4f Oa[4];
    #pragma unroll
    for (int t = 0; t < 4; ++t) Oa[t] = (v4f){0.f, 0.f, 0.f, 0.f};
    float la[4] = {0.f, 0.f, 0.f, 0.f};

    // ---- Main flash loop over key tiles ----
    for (int j0 = 0; j0 < Ss; j0 += 64) {
        __syncthreads();   // B1: prev iter PV reads (Pt=Kt, V=Rt) done
        uint4 v0v, v1v;
        {
            const uint4* sk = (const uint4*)(qkv + (size_t)(b * Ss + j0 + sgr) * QKVLD + NHh + n * 64 + scg * 8);
            const uint4* sr = (const uint4*)(r16 + (size_t)(b * Rr + (j0 + c0) + sgr) * NHh + n * 64 + scg * 8);
            const uint4* sv = (const uint4*)(vT16 + (size_t)(bn * 64 + sgr) * Ss + j0 + scg * 8);
            uint4 k0v = sk[0], k1v = sk[1];
            uint4 r0v = sr[0], r1v = sr[1];
            v0v = sv[0]; v1v = sv[1];
            *(uint4*)kd0 = k0v;  *(uint4*)kd1 = k1v;
            *(uint4*)rd0 = r0v;  *(uint4*)rd1 = r1v;
        }
        __syncthreads();   // B2: K/R stage visible

        const v4f z = (v4f){0.f, 0.f, 0.f, 0.f};
        // Content scores
        v4f sc[4];
        #pragma unroll
        for (int t = 0; t < 4; ++t) {
            const int row = t * 16 + l15;
            v8s bk0 = *(const v8s*)&Kt[row * 64 + ((quad ^ l7) << 3)];
            v8s bk1 = *(const v8s*)&Kt[row * 64 + (((quad + 4) ^ l7) << 3)];
            sc[t] = __builtin_amdgcn_mfma_f32_16x16x32_bf16(aqc0, bk0, z, 0, 0, 0);
            sc[t] = __builtin_amdgcn_mfma_f32_16x16x32_bf16(aqc1, bk1, sc[t], 0, 0, 0);
        }
        // Pos chunk -> ring (skewed cm: col = j & 127, row-XOR swizzle)
        #pragma unroll
        for (int t = 0; t < 4; ++t) {
            const int row = t * 16 + l15;
            v8s br0 = *(const v8s*)&Rt[row * 64 + ((quad ^ l7) << 3)];
            v8s br1 = *(const v8s*)&Rt[row * 64 + (((quad + 4) ^ l7) << 3)];
            v4f pp = __builtin_amdgcn_mfma_f32_16x16x32_bf16(aqp0, br0, z, 0, 0, 0);
            pp = __builtin_amdgcn_mfma_f32_16x16x32_bf16(aqp1, br1, pp, 0, 0, 0);
            const int colbase = j0 + t * 16 + l15;
            #pragma unroll
            for (int v = 0; v < 4; ++v) {
                const int irow = w16 + quad * 4 + v;
                const int col = (colbase + irow) & 127;
                ring[col * 64 + (irow ^ ((col & 7) << 3))] = f2bf(pp[v]);
            }
        }

        __syncthreads();   // B3: all waves' Kt+Rt reads done -> overlays may write

        // V (held in regs since stage) -> Rt overlay
        *(uint4*)rd0 = v0v;
        *(uint4*)rd1 = v1v;

        // Scores -> exp2 -> Pt (=Kt); pos gathered via one b64 per t
        #pragma unroll
        for (int t = 0; t < 4; ++t) {
            const int col = (j0 + t * 16 + l15) & 127;
            const int rbase = (w16 + quad * 4) ^ ((col & 7) << 3);
            const v4us pr = *(const v4us*)&ring[col * 64 + rbase];
            const int j = t * 16 + l15;
            const int gsw = j >> 3;            // 2t + (l15>>3)
            #pragma unroll
            for (int v = 0; v < 4; ++v) {
                const int irow = w16 + quad * 4 + v;
                const float p = exp2f(sc[t][v] + bf2f(pr[v]));
                la[v] += p;
                Pt[irow * 64 + (((gsw ^ (irow & 7)) << 3) | (j & 7))] = f2bf(p);
            }
        }

        __syncthreads();   // B4: V stage + Pt visible

        // PV (Pt rows are wave-private; V rows need all threads -> B4)
        v8s pa0 = *(v8s*)&Pt[(w16 + l15) * 64 + ((quad ^ l7) << 3)];
        v8s pa1 = *(v8s*)&Pt[(w16 + l15) * 64 + (((quad + 4) ^ l7) << 3)];
        __builtin_amdgcn_s_setprio(1);
        #pragma unroll
        for (int ht = 0; ht < 4; ++ht) {
            const int row = ht * 16 + l15;
            v8s bv0 = *(const v8s*)&Rt[row * 64 + ((quad ^ l7) << 3)];
            v8s bv1 = *(const v8s*)&Rt[row * 64 + (((quad + 4) ^ l7) << 3)];
            Oa[ht] = __builtin_amdgcn_mfma_f32_16x16x32_bf16(pa0, bv0, Oa[ht], 0, 0, 0);
            Oa[ht] = __builtin_amdgcn_mfma_f32_16x16x32_bf16(pa1, bv1, Oa[ht], 0, 0, 0);
        }
        __builtin_amdgcn_s_setprio(0);
    }

    // ---- Epilogue: reduce row sums across quad, normalize, store ----
    #pragma unroll
    for (int v = 0; v < 4; ++v) {
        la[v] += __shfl_xor(la[v], 1);
        la[v] += __shfl_xor(la[v], 2);
        la[v] += __shfl_xor(la[v], 4);
        la[v] += __shfl_xor(la[v], 8);
        la[v] = 1.f / la[v];
    }
    #pragma unroll
    for (int ht = 0; ht < 4; ++ht) {
        #pragma unroll
        for (int v = 0; v < 4; ++v) {
            const int irow = w16 + quad * 4 + v;
            attn[(size_t)(b * Ss + i0 + irow) * NHh + n * 64 + ht * 16 + l15] =
                f2bf(Oa[ht][v] * la[v]);
        }
    }
}

// ---------------------------------------------------------------------------
// Fused residual-add + LayerNorm over E=1024; optional bf16 copy of output.
// float4/ushort4 vectorized (G13) — 16 B/lane loads and stores.
// ---------------------------------------------------------------------------
template<int W16>
__global__ __launch_bounds__(256) void add_ln_kernel(
    const float* __restrict__ a, const float* __restrict__ res,
    const float* __restrict__ g, const float* __restrict__ bet,
    float* __restrict__ out, us* __restrict__ out16)
{
    const int row = blockIdx.x;
    const int tid = threadIdx.x;
    const int idx = tid * 4;
    const float4 va = *reinterpret_cast<const float4*>(a   + (size_t)row * Ee + idx);
    const float4 vr = *reinterpret_cast<const float4*>(res + (size_t)row * Ee + idx);

    float vals[4];
    vals[0] = va.x + vr.x; vals[1] = va.y + vr.y;
    vals[2] = va.z + vr.z; vals[3] = va.w + vr.w;
    float lsum = 0.f, lsq = 0.f;
    #pragma unroll
    for (int it = 0; it < 4; ++it) {
        lsum += vals[it];
        lsq  = fmaf(vals[it], vals[it], lsq);
    }
    #pragma unroll
    for (int off = 32; off > 0; off >>= 1) {
        lsum += __shfl_down(lsum, off);
        lsq  += __shfl_down(lsq,  off);
    }
    __shared__ float w1[4], w2[4];
    if ((tid & 63) == 0) { w1[tid >> 6] = lsum; w2[tid >> 6] = lsq; }
    __syncthreads();
    const float sum  = w1[0] + w1[1] + w1[2] + w1[3];
    const float sq   = w2[0] + w2[1] + w2[2] + w2[3];
    const float mean = sum * (1.f / 1024.f);
    const float var  = sq * (1.f / 1024.f) - mean * mean;
    const float rstd = rsqrtf(var + 1e-12f);

    const float4 vg = *reinterpret_cast<const float4*>(g   + idx);
    const float4 vb = *reinterpret_cast<const float4*>(bet + idx);
    float4 o;
    o.x = (vals[0] - mean) * rstd * vg.x + vb.x;
    o.y = (vals[1] - mean) * rstd * vg.y + vb.y;
    o.z = (vals[2] - mean) * rstd * vg.z + vb.z;
    o.w = (vals[3] - mean) * rstd * vg.w + vb.w;
    *reinterpret_cast<float4*>(out + (size_t)row * Ee + idx) = o;
    if (W16) {
        ushort4 o16;
        o16.x = f2bf(o.x); o16.y = f2bf(o.y);
        o16.z = f2bf(o.z); o16.w = f2bf(o.w);
        *reinterpret_cast<ushort4*>(out16 + (size_t)row * Ee + idx) = o16;
    }
}

// ---------------------------------------------------------------------------
// Orchestration. Workspace layout (1 MB units), 90 MB total:
//   [ 0, 8)  x16      -> attn16 (ph3)  -> inner16 head (ph6)
//   [ 8,24)  rpe16    -> vT16 [8,16) (ph2.5), ao fp32 [16,24) (ph4)
//   [24,30)  Wqkv_t   [30,32) Wr_t   [32,34) Wo_t      (inner16 covers 0..32)
//   [34,42)  Wi_t     [42,50) Wout_t
//   [50,74)  qkv16    -> h16 [50,58) + hb fp32 [58,74) (ph5)
//   [74,90)  r16      -> out2 fp32 (ph7)
// ---------------------------------------------------------------------------
#define MB (1u << 20)

extern "C" void kernel_launch(void* const* d_in, const int* in_sizes, int n_in,
                              void* d_out, int out_size, void* d_ws, size_t ws_size,
                              hipStream_t stream)
{
    (void)in_sizes; (void)n_in; (void)out_size; (void)ws_size;

    const float* x    = (const float*)d_in[0];
    const float* cbf  = (const float*)d_in[1];
    const float* pbf  = (const float*)d_in[2];
    const float* rpe  = (const float*)d_in[3];
    const float* Wq   = (const float*)d_in[4];
    const float* Wk   = (const float*)d_in[5];
    const float* Wv   = (const float*)d_in[6];
    const float* Wr   = (const float*)d_in[7];
    const float* Wo   = (const float*)d_in[8];
    const float* ln1g = (const float*)d_in[9];
    const float* ln1b = (const float*)d_in[10];
    const float* Wi   = (const float*)d_in[11];
    const float* bi   = (const float*)d_in[12];
    const float* Wout = (const float*)d_in[13];
    const float* bout = (const float*)d_in[14];
    const float* ln2g = (const float*)d_in[15];
    const float* ln2b = (const float*)d_in[16];

    float* out = (float*)d_out;
    char*  ws  = (char*)d_ws;

    us* x16    = (us*)(ws + 0 * MB);
    us* rpe16  = (us*)(ws + 8 * MB);
    us* Wqkv_t = (us*)(ws + 24 * MB);           // [3072][1024]
    us* Wr_t   = (us*)(ws + 30 * MB);
    us* Wo_t   = (us*)(ws + 32 * MB);
    us* Wi_t   = (us*)(ws + 34 * MB);
    us* Wout_t = (us*)(ws + 42 * MB);
    us* qkv16  = (us*)(ws + 50 * MB);           // [BS][3072]
    us* r16    = (us*)(ws + 74 * MB);
    us* vT16   = (us*)(ws + 8 * MB);            // reuse rpe16 (after qkv_r gemm)
    us* attn16 = (us*)(ws + 0 * MB);            // reuse x16
    float* ao  = (float*)(ws + 16 * MB);        // [16,24)
    us* h16    = (us*)(ws + 50 * MB);           // reuse qkv16
    float* hb  = (float*)(ws + 58 * MB);        // reuse qkv16 tail
    us* inner16= (us*)(ws + 0 * MB);            // 0..32 MB
    float* out2= (float*)(ws + 74 * MB);        // reuse r16

    const dim3 blk(256);

    // Phase 1: all converts + transposes, one dispatch
    prep_all<<<dim3(25600), blk, 0, stream>>>(
        x, x16, rpe, rpe16, Wq, Wk, Wv, Wr, Wo,
        Wqkv_t, Wr_t, Wo_t, Wi, Wi_t, Wout, Wout_t);

    // Phase 2: fused QKV + R projection (one 1280-block dispatch)
    gemm_qkv_r<<<dim3(1280), blk, 0, stream>>>(x16, Wqkv_t, qkv16, rpe16, Wr_t, r16);

    // Phase 2.5: V transpose (v cols of qkv) -> [B,N,H,S]
    transpose_v<<<dim3(16, 64), blk, 0, stream>>>(qkv16 + 2048, vT16, QKVLD);

    // Phase 3: MFMA flash attention; grid (bn, i) for XCD-local K/R/V reuse
    attn_mfma<<<dim3(64, 16), blk, 0, stream>>>(qkv16, vT16, r16, cbf, pbf, attn16);

    // Phase 4: output projection (fp32 out), 64-row tiles -> 512 blocks (2/CU)
    gemm_tile<2,0,0,0><<<dim3(8, 64), blk, 0, stream>>>(attn16, Wo_t, nullptr, ao, NHh, Ee);

    // Phase 5: h = LN1(ao + x), fp32 + bf16
    add_ln_kernel<1><<<dim3(BSs), blk, 0, stream>>>(ao, x, ln1g, ln1b, hb, h16);

    // Phase 6: FFN1 (bias+relu, bf16 out), 128-row tiles, 1024 blocks
    gemm_tile<4,1,1,1><<<dim3(32, 32), blk, 0, stream>>>(h16, Wi_t, bi, inner16, Ee, Ff);

    // Phase 7: FFN2 (bias, fp32 out), 64-row tiles -> 512 blocks (2+/CU)
    gemm_tile<2,0,1,0><<<dim3(8, 64), blk, 0, stream>>>(inner16, Wout_t, bout, out2, Ff, Ee);

    // Phase 8: out = LN2(out2 + h)
    add_ln_kernel<0><<<dim3(BSs), blk, 0, stream>>>(out2, hb, ln2g, ln2b, out, nullptr);
}